// Round 7
// baseline (426.515 us; speedup 1.0000x reference)
//
#include <hip/hip_runtime.h>
#include <math.h>

#define DEPTH 6
#define HEADS 8
#define BB    2
#define NN    128
#define EE    160
#define NF    127
#define DIMM  128
#define INNER 512

#define KV_SLAB (BB * NN * INNER)   // floats per k/v slab

__device__ __forceinline__ void fma4(float4& acc, float a, const float4 w) {
    acc.x += a * w.x; acc.y += a * w.y; acc.z += a * w.z; acc.w += a * w.w;
}

// 1024-thread (16-wave) block sum; result broadcast.
__device__ __forceinline__ float block_reduce_sum_16w(float val, float* sbuf16) {
#pragma unroll
    for (int off = 32; off > 0; off >>= 1) val += __shfl_xor(val, off, 64);
    int wave = threadIdx.x >> 6;
    if ((threadIdx.x & 63) == 0) sbuf16[wave] = val;
    __syncthreads();
    float r = 0.0f;
#pragma unroll
    for (int w = 0; w < 16; w++) r += sbuf16[w];
    __syncthreads();
    return r;
}

// LN over 128 dims + QKV projection for node bn. 1024 threads.
// Per-thread: out-quad c7 = t&127 per stream, K-group kg = t>>7 (8 groups x 16).
// s_arena >= 12288 floats for partials.
__device__ void ln_qkv_16w(float nd, bool own, int t, int bn, int layer,
                           const float* ln_g, const float* ln_b,
                           const float* Wq, const float* bq,
                           const float* Wkv, const float* bkv,
                           float* qout, float* kout, float* vout,
                           float* s_xn, float* s_red, float* s_arena) {
    int d = t & 127;
    float m   = block_reduce_sum_16w(own ? nd : 0.0f, s_red) * (1.0f / 128.0f);
    float df  = nd - m;
    float var = block_reduce_sum_16w(own ? df * df : 0.0f, s_red) * (1.0f / 128.0f);
    float xn  = df * rsqrtf(var + 1e-5f) * ln_g[layer * DIMM + d] + ln_b[layer * DIMM + d];
    if (own) s_xn[d] = xn;
    __syncthreads();

    int c7  = t & 127;
    int kg  = t >> 7;        // 0..7
    int kkb = kg * 16;
    const float4* WqR  = (const float4*)(Wq  + (size_t)layer * DIMM * INNER);
    const float4* WkvR = (const float4*)(Wkv + (size_t)layer * DIMM * 2 * INNER);
    float4 aq = {0,0,0,0}, ak = {0,0,0,0}, av = {0,0,0,0};
#pragma unroll
    for (int base = 0; base < 16; base += 8) {
        float4 wq[8], wk[8], wv[8];
#pragma unroll
        for (int p = 0; p < 8; p++) {
            int kk = kkb + base + p;
            wq[p] = WqR[kk * 128 + c7];
            wk[p] = WkvR[kk * 256 + c7];
            wv[p] = WkvR[kk * 256 + 128 + c7];
        }
#pragma unroll
        for (int p = 0; p < 8; p++) {
            float a = s_xn[kkb + base + p];
            fma4(aq, a, wq[p]); fma4(ak, a, wk[p]); fma4(av, a, wv[p]);
        }
    }
    ((float4*)(s_arena + (0 * 8 + kg) * 512))[c7] = aq;
    ((float4*)(s_arena + (1 * 8 + kg) * 512))[c7] = ak;
    ((float4*)(s_arena + (2 * 8 + kg) * 512))[c7] = av;
    __syncthreads();
    // combine: 1536 outputs; thread t does (stream = t>>9, o = t&511);
    // threads < 512 also do stream 2, output t.
    {
        int o  = t & 511;
        int st = t >> 9;     // 0 or 1
        float bias = (st == 0) ? bq[layer * INNER + o] : bkv[layer * 2 * INNER + o];
        float acc = bias;
#pragma unroll
        for (int g = 0; g < 8; g++) acc += s_arena[(st * 8 + g) * 512 + o];
        if (st == 0) qout[(size_t)bn * INNER + o] = acc;
        else         kout[(size_t)bn * INNER + o] = acc;
        if (t < 512) {
            float acc2 = bkv[layer * 2 * INNER + INNER + t];
#pragma unroll
            for (int g = 0; g < 8; g++) acc2 += s_arena[(2 * 8 + g) * 512 + t];
            vout[(size_t)bn * INNER + t] = acc2;
        }
    }
    __syncthreads();
}

// ---------- kernels ----------

__global__ __launch_bounds__(1024)
__attribute__((amdgpu_waves_per_eu(4, 4)))
void k_pre(const int* indices, const float* noise,
           const float* atom_emb,
           const float* ln1_g, const float* ln1_b,
           const float* Wq, const float* bq,
           const float* Wkv, const float* bkv,
           float* nodes, float* qb, float* kb, float* vb) {
    int bn = blockIdx.x;
    int t  = threadIdx.x;
    int d  = t & 127;
    bool own = (t < 128);
    __shared__ float s_xn[128];
    __shared__ float s_red[16];
    __shared__ float s_arena[12288];
    float nd = 0.0f;
    if (own) {
        int idx = indices[bn];
        nd = (d < NF) ? atom_emb[idx * NF + d] : noise[0];
        nodes[bn * DIMM + d] = nd;
    }
    ln_qkv_16w(nd, own, t, bn, 0, ln1_g, ln1_b, Wq, bq, Wkv, bkv, qb, kb, vb,
               s_xn, s_red, s_arena);
}

// Fused per-layer kernel, 1024 threads: attention + post pipeline + next-layer QKV.
__global__ __launch_bounds__(1024)
__attribute__((amdgpu_waves_per_eu(4, 4)))
void k_layer(int layer,
        const float* coords, const int* bonds,
        const float* We, const float* be,
        float* qb, const float* kin, const float* vin,
        float* kout, float* vout,
        const float* Wo, const float* bo, const float* Wg1,
        const float* ln2_g, const float* ln2_b,
        const float* W1, const float* b1,
        const float* W2, const float* b2,
        const float* Wg2,
        const float* ln1_g, const float* ln1_b,
        const float* Wq, const float* bq,
        const float* Wkv, const float* bkv,
        float* nodes) {
    int bn = blockIdx.x;
    int b = bn >> 7, i = bn & 127;
    int t = threadIdx.x;
    int d = t & 127;
    bool own = (t < 128);

    __shared__ float scoord[3 * NN];
    __shared__ float sedge[3 * NN];
    __shared__ int   sadj[NN];
    __shared__ float s_l[8 * HEADS];
    __shared__ float s_ao[INNER];
    __shared__ float s_h[INNER];
    __shared__ float s_xn[128];
    __shared__ float s_red[16];
    __shared__ float s_arena[12288];   // phase A: s_o[8][512]; phase B: GEMV partials

    // ---------- Phase A: attention ----------
    int jg = t >> 7;     // 0..7, each handles 16 j's
    int c  = t & 127;    // head-dim quad; head h = c>>4
    int h  = c >> 4;

    const float4* qR  = (const float4*)(qb + (size_t)bn * INNER);
    const float4* WeR = (const float4*)(We + (size_t)layer * 3 * INNER);
    float4 qv  = qR[c];
    float4 we0 = WeR[c], we1 = WeR[128 + c], we2 = WeR[256 + c];
    float4 bev = ((const float4*)(be + (size_t)layer * INNER))[c];
    float res = own ? nodes[bn * DIMM + d] : 0.0f;

    if (t < 3 * NN) scoord[t] = coords[b * 3 * NN + t];
    if (t < NN) sadj[t] = 0;
    __syncthreads();
    if (t < EE) {
        int e0 = bonds[2 * t], e1 = bonds[2 * t + 1];
        if (e0 == i) sadj[e1] = 1;
        if (e1 == i) sadj[e0] = 1;
    }
    __syncthreads();
    if (t < NN) {
        int j = t;
        float msk = sadj[j] ? 1.0f : 0.0f;
        sedge[3 * j + 0] = msk * (scoord[3 * i + 0] - scoord[3 * j + 0]);
        sedge[3 * j + 1] = msk * (scoord[3 * i + 1] - scoord[3 * j + 1]);
        sedge[3 * j + 2] = msk * (scoord[3 * i + 2] - scoord[3 * j + 2]);
    }
    __syncthreads();

    const float4* kR = (const float4*)(kin + (size_t)b * NN * INNER);
    const float4* vR = (const float4*)(vin + (size_t)b * NN * INNER);

    float l_run = 0.0f;
    float4 o_run = {0, 0, 0, 0};
    int j0 = jg * 16;
#pragma unroll
    for (int base = 0; base < 16; base += 8) {
        float4 kvv[8], vvv[8];
#pragma unroll
        for (int p = 0; p < 8; p++) {
            int j = j0 + base + p;
            kvv[p] = kR[j * 128 + c];
            vvv[p] = vR[j * 128 + c];
        }
#pragma unroll
        for (int p = 0; p < 8; p++) {
            int j = j0 + base + p;
            float ex = sedge[3 * j], ey = sedge[3 * j + 1], ez = sedge[3 * j + 2];
            float4 e;
            e.x = bev.x + ex * we0.x + ey * we1.x + ez * we2.x;
            e.y = bev.y + ex * we0.y + ey * we1.y + ez * we2.y;
            e.z = bev.z + ex * we0.z + ey * we1.z + ez * we2.z;
            e.w = bev.w + ex * we0.w + ey * we1.w + ez * we2.w;
            float4 kv = kvv[p];
            float s = (qv.x * (kv.x + e.x) + qv.y * (kv.y + e.y))
                    + (qv.z * (kv.z + e.z) + qv.w * (kv.w + e.w));
            s += __shfl_xor(s, 1, 64);
            s += __shfl_xor(s, 2, 64);
            s += __shfl_xor(s, 4, 64);
            s += __shfl_xor(s, 8, 64);
            float pp = __expf(s * 0.125f);
            float4 vv = vvv[p];
            l_run += pp;
            o_run.x += pp * (vv.x + e.x);
            o_run.y += pp * (vv.y + e.y);
            o_run.z += pp * (vv.z + e.z);
            o_run.w += pp * (vv.w + e.w);
        }
    }
    ((float4*)(s_arena + jg * INNER))[c] = o_run;
    if ((c & 15) == 0) s_l[jg * HEADS + h] = l_run;
    __syncthreads();
    if (jg == 0) {
        float4 o = o_run;
        float l = l_run;
#pragma unroll
        for (int g = 1; g < 8; g++) {
            float4 og = ((float4*)(s_arena + g * INNER))[c];
            o.x += og.x; o.y += og.y; o.z += og.z; o.w += og.w;
            l += s_l[g * HEADS + h];
        }
        float inv = 1.0f / l;
        float4 rr; rr.x = o.x * inv; rr.y = o.y * inv; rr.z = o.z * inv; rr.w = o.w * inv;
        ((float4*)s_ao)[c] = rr;
    }
    __syncthreads();

    // ---------- Phase B: post pipeline ----------
    // Wo-proj: 128 outs, K=512. c5 = out quad (32), kg32 = t>>5 (32 groups x 16).
    int c5   = t & 31;
    int kg32 = t >> 5;
    {
        const float4* WoR = (const float4*)(Wo + (size_t)layer * INNER * DIMM);
        int kkb = kg32 * 16;
        float4 acc = {0, 0, 0, 0};
#pragma unroll
        for (int base = 0; base < 16; base += 8) {
            float4 w[8];
#pragma unroll
            for (int p = 0; p < 8; p++) w[p] = WoR[(kkb + base + p) * 32 + c5];
#pragma unroll
            for (int p = 0; p < 8; p++) fma4(acc, s_ao[kkb + base + p], w[p]);
        }
        ((float4*)(s_arena + kg32 * 128))[c5] = acc;
    }
    __syncthreads();
    float x = 0.0f;
    if (own) {
        x = bo[layer * DIMM + d];
#pragma unroll
        for (int g = 0; g < 32; g++) x += s_arena[g * 128 + d];
    }

    // gated residual 1
    const float* Wg1_l = Wg1 + layer * 3 * DIMM;
    float texpr = own ? (x * Wg1_l[d] + res * Wg1_l[DIMM + d] + (x - res) * Wg1_l[2 * DIMM + d]) : 0.0f;
    float g1 = block_reduce_sum_16w(texpr, s_red);
    g1 = 1.0f / (1.0f + __expf(-g1));
    float n1 = x * g1 + res * (1.0f - g1);

    // LN2
    float m   = block_reduce_sum_16w(own ? n1 : 0.0f, s_red) * (1.0f / 128.0f);
    float df  = n1 - m;
    float var = block_reduce_sum_16w(own ? df * df : 0.0f, s_red) * (1.0f / 128.0f);
    float xn  = df * rsqrtf(var + 1e-5f) * ln2_g[layer * DIMM + d] + ln2_b[layer * DIMM + d];
    if (own) s_xn[d] = xn;
    __syncthreads();

    // FF1 + exact gelu: 512 outs, K=128. c7 = out quad (128), kg8 = t>>7 (8 x 16).
    int c7  = t & 127;
    int kg8 = t >> 7;
    {
        const float4* W1R = (const float4*)(W1 + (size_t)layer * DIMM * 4 * DIMM);
        int kkb = kg8 * 16;
        float4 acc = {0, 0, 0, 0};
#pragma unroll
        for (int base = 0; base < 16; base += 8) {
            float4 w[8];
#pragma unroll
            for (int p = 0; p < 8; p++) w[p] = W1R[(kkb + base + p) * 128 + c7];
#pragma unroll
            for (int p = 0; p < 8; p++) fma4(acc, s_xn[kkb + base + p], w[p]);
        }
        ((float4*)(s_arena + kg8 * 512))[c7] = acc;
    }
    __syncthreads();
    if (t < 512) {
        float a = b1[layer * 4 * DIMM + t];
#pragma unroll
        for (int g = 0; g < 8; g++) a += s_arena[g * 512 + t];
        a = 0.5f * a * (1.0f + erff(a * 0.70710678f));
        s_h[t] = a;
    }
    __syncthreads();

    // FF2: 128 outs, K=512 (same split as Wo)
    {
        const float4* W2R = (const float4*)(W2 + (size_t)layer * 4 * DIMM * DIMM);
        int kkb = kg32 * 16;
        float4 acc = {0, 0, 0, 0};
#pragma unroll
        for (int base = 0; base < 16; base += 8) {
            float4 w[8];
#pragma unroll
            for (int p = 0; p < 8; p++) w[p] = W2R[(kkb + base + p) * 32 + c5];
#pragma unroll
            for (int p = 0; p < 8; p++) fma4(acc, s_h[kkb + base + p], w[p]);
        }
        ((float4*)(s_arena + kg32 * 128))[c5] = acc;
    }
    __syncthreads();
    float y = 0.0f;
    if (own) {
        y = b2[layer * DIMM + d];
#pragma unroll
        for (int g = 0; g < 32; g++) y += s_arena[g * 128 + d];
    }

    // gated residual 2
    const float* Wg2_l = Wg2 + layer * 3 * DIMM;
    texpr = own ? (y * Wg2_l[d] + n1 * Wg2_l[DIMM + d] + (y - n1) * Wg2_l[2 * DIMM + d]) : 0.0f;
    float g2 = block_reduce_sum_16w(texpr, s_red);
    g2 = 1.0f / (1.0f + __expf(-g2));
    float n2 = y * g2 + n1 * (1.0f - g2);
    if (own) nodes[bn * DIMM + d] = n2;

    if (layer < DEPTH - 1) {
        ln_qkv_16w(own ? n2 : 0.0f, own, t, bn, layer + 1, ln1_g, ln1_b, Wq, bq, Wkv, bkv,
                   qb, kout, vout, s_xn, s_red, s_arena);
    }
}

// Final: sum over nodes of (nodes @ Wlin + blin) -> scalar.
__global__ __launch_bounds__(256) void k_final(const float* nodes, const float* Wlin,
                                               const float* blin, float* out) {
    int t = threadIdx.x; // node index
    __shared__ float s_w[DIMM];
    if (t < DIMM) s_w[t] = Wlin[t];
    __syncthreads();
    float s = blin[0];
    const float4* nr = (const float4*)(nodes + t * DIMM);
#pragma unroll 8
    for (int q = 0; q < 32; q++) {
        float4 n = nr[q];
        s += n.x * s_w[4 * q] + n.y * s_w[4 * q + 1] + n.z * s_w[4 * q + 2] + n.w * s_w[4 * q + 3];
    }
#pragma unroll
    for (int off = 32; off > 0; off >>= 1) s += __shfl_xor(s, off, 64);
    __shared__ float sb[4];
    int wave = t >> 6, lane = t & 63;
    if (lane == 0) sb[wave] = s;
    __syncthreads();
    if (t == 0) out[0] = sb[0] + sb[1] + sb[2] + sb[3];
}

extern "C" void kernel_launch(void* const* d_in, const int* in_sizes, int n_in,
                              void* d_out, int out_size, void* d_ws, size_t ws_size,
                              hipStream_t stream) {
    const int*   indices = (const int*)d_in[0];
    const float* coords  = (const float*)d_in[1];
    const int*   bonds   = (const int*)d_in[2];
    const float* noise   = (const float*)d_in[3];
    const float* atom_emb= (const float*)d_in[4];
    const float* ln1_g   = (const float*)d_in[5];
    const float* ln1_b   = (const float*)d_in[6];
    const float* Wq      = (const float*)d_in[7];
    const float* bq      = (const float*)d_in[8];
    const float* Wkv     = (const float*)d_in[9];
    const float* bkv     = (const float*)d_in[10];
    const float* We      = (const float*)d_in[11];
    const float* be      = (const float*)d_in[12];
    const float* Wo      = (const float*)d_in[13];
    const float* bo      = (const float*)d_in[14];
    const float* Wg1     = (const float*)d_in[15];
    const float* ln2_g   = (const float*)d_in[16];
    const float* ln2_b   = (const float*)d_in[17];
    const float* W1      = (const float*)d_in[18];
    const float* b1      = (const float*)d_in[19];
    const float* W2      = (const float*)d_in[20];
    const float* b2      = (const float*)d_in[21];
    const float* Wg2     = (const float*)d_in[22];
    const float* Wlin    = (const float*)d_in[23];
    const float* blin    = (const float*)d_in[24];

    float* ws    = (float*)d_ws;
    float* nodes = ws;                       // 32768 floats
    float* qb    = nodes + BB * NN * DIMM;   // 131072 floats
    float* kb    = qb + KV_SLAB;             // 2 slabs
    float* vb    = kb + 2 * KV_SLAB;         // 2 slabs

    k_pre<<<BB * NN, 1024, 0, stream>>>(indices, noise, atom_emb, ln1_g, ln1_b,
                                        Wq, bq, Wkv, bkv, nodes, qb, kb, vb);
    for (int l = 0; l < DEPTH; l++) {
        const float* kin = kb + (size_t)(l & 1) * KV_SLAB;
        const float* vin = vb + (size_t)(l & 1) * KV_SLAB;
        float* kout = kb + (size_t)((l + 1) & 1) * KV_SLAB;
        float* vout = vb + (size_t)((l + 1) & 1) * KV_SLAB;
        k_layer<<<BB * NN, 1024, 0, stream>>>(l, coords, bonds, We, be,
                                              qb, kin, vin, kout, vout,
                                              Wo, bo, Wg1, ln2_g, ln2_b, W1, b1, W2, b2,
                                              Wg2, ln1_g, ln1_b, Wq, bq, Wkv, bkv, nodes);
    }
    k_final<<<1, 256, 0, stream>>>(nodes, Wlin, blin, (float*)d_out);
}

// Round 8
// 312.552 us; speedup vs baseline: 1.3646x; 1.3646x over previous
//
#include <hip/hip_runtime.h>
#include <math.h>

#define DEPTH 6
#define HEADS 8
#define BB    2
#define NN    128
#define EE    160
#define NF    127
#define DIMM  128
#define INNER 512

#define KV_SLAB (BB * NN * INNER)   // floats per k/v slab

__device__ __forceinline__ void fma4(float4& acc, float a, const float4 w) {
    acc.x += a * w.x; acc.y += a * w.y; acc.z += a * w.z; acc.w += a * w.w;
}

// 512-thread (8-wave) block sum; result broadcast.
__device__ __forceinline__ float block_reduce_sum_8w(float val, float* sbuf) {
#pragma unroll
    for (int off = 32; off > 0; off >>= 1) val += __shfl_xor(val, off, 64);
    int wave = threadIdx.x >> 6;
    if ((threadIdx.x & 63) == 0) sbuf[wave] = val;
    __syncthreads();
    float r = sbuf[0] + sbuf[1] + sbuf[2] + sbuf[3] + sbuf[4] + sbuf[5] + sbuf[6] + sbuf[7];
    __syncthreads();
    return r;
}

// LN over 128 dims + QKV projection for node bn. 512 threads, 8-deep
// register-prefetch batches (VGPR-safe).
__device__ void ln_qkv_pf(float nd, bool own, int t, int bn, int layer,
                          const float* ln_g, const float* ln_b,
                          const float* Wq, const float* bq,
                          const float* Wkv, const float* bkv,
                          float* qout, float* kout, float* vout,
                          float* s_xn, float* s_red, float* s_part) {
    int d = t & 127;
    float m   = block_reduce_sum_8w(own ? nd : 0.0f, s_red) * (1.0f / 128.0f);
    float df  = nd - m;
    float var = block_reduce_sum_8w(own ? df * df : 0.0f, s_red) * (1.0f / 128.0f);
    float xn  = df * rsqrtf(var + 1e-5f) * ln_g[layer * DIMM + d] + ln_b[layer * DIMM + d];
    if (own) s_xn[d] = xn;
    __syncthreads();

    int c7  = t & 127;
    int kg  = t >> 7;    // 4 K-groups of 32
    int kkb = kg * 32;
    const float4* WqR  = (const float4*)(Wq  + (size_t)layer * DIMM * INNER);
    const float4* WkvR = (const float4*)(Wkv + (size_t)layer * DIMM * 2 * INNER);
    float4 aq = {0,0,0,0}, ak = {0,0,0,0}, av = {0,0,0,0};
#pragma unroll
    for (int base = 0; base < 32; base += 8) {
        float4 wq[8], wk[8], wv[8];
#pragma unroll
        for (int p = 0; p < 8; p++) {
            int kk = kkb + base + p;
            wq[p] = WqR[kk * 128 + c7];
            wk[p] = WkvR[kk * 256 + c7];
            wv[p] = WkvR[kk * 256 + 128 + c7];
        }
#pragma unroll
        for (int p = 0; p < 8; p++) {
            float a = s_xn[kkb + base + p];
            fma4(aq, a, wq[p]); fma4(ak, a, wk[p]); fma4(av, a, wv[p]);
        }
    }
    ((float4*)(s_part + (0 * 4 + kg) * 512))[c7] = aq;
    ((float4*)(s_part + (1 * 4 + kg) * 512))[c7] = ak;
    ((float4*)(s_part + (2 * 4 + kg) * 512))[c7] = av;
    __syncthreads();
    float q = bq[layer * INNER + t];
    float k = bkv[layer * 2 * INNER + t];
    float v = bkv[layer * 2 * INNER + INNER + t];
#pragma unroll
    for (int g = 0; g < 4; g++) {
        q += s_part[(0 * 4 + g) * 512 + t];
        k += s_part[(1 * 4 + g) * 512 + t];
        v += s_part[(2 * 4 + g) * 512 + t];
    }
    qout[(size_t)bn * INNER + t] = q;
    kout[(size_t)bn * INNER + t] = k;
    vout[(size_t)bn * INNER + t] = v;
}

// ---------- kernels ----------

// Warm the entire weight set into L3 at HBM bandwidth (not latency-chained).
// 256 blocks x 512 threads x 5 float4 covers 9.5 MB.
__global__ __launch_bounds__(512) void k_warm(const float* Wq, const float* Wkv,
                                              const float* Wo, const float* W1,
                                              const float* W2, const float* We,
                                              const float* atom_emb, float* dump) {
    int tid = blockIdx.x * 512 + threadIdx.x;
    float s = 0.0f;
#pragma unroll
    for (int p = 0; p < 5; p++) {
        int g = tid + p * 131072;
        const float4* src = nullptr;
        int off = 0;
        if (g < 98304)        { src = (const float4*)Wq;  off = g; }
        else if (g < 294912)  { src = (const float4*)Wkv; off = g - 98304; }
        else if (g < 393216)  { src = (const float4*)Wo;  off = g - 294912; }
        else if (g < 491520)  { src = (const float4*)W1;  off = g - 393216; }
        else if (g < 589824)  { src = (const float4*)W2;  off = g - 491520; }
        else if (g < 592128)  { src = (const float4*)We;  off = g - 589824; }
        else if (g < 595303)  { src = (const float4*)atom_emb; off = g - 592128; }
        if (src) {
            float4 v = src[off];
            s += v.x + v.y + v.z + v.w;
        }
    }
    if (s == 1.602176634e+30f) dump[0] = s;   // never true; defeats DCE
}

__global__ __launch_bounds__(512, 2) void k_pre(const int* indices, const float* noise,
                                                const float* atom_emb,
                                                const float* ln1_g, const float* ln1_b,
                                                const float* Wq, const float* bq,
                                                const float* Wkv, const float* bkv,
                                                const float* Wo, const float* W1,
                                                const float* W2,
                                                float* nodes, float* qb, float* kb, float* vb) {
    int bn = blockIdx.x;
    int t  = threadIdx.x;
    int d  = t & 127;
    bool own = (t < 128);
    __shared__ float s_xn[128];
    __shared__ float s_red[8];
    __shared__ float s_part[6144];

    // L2 prefetch of layer-0 Wo/W1/W2 (stripe per 8-block XCD group)
    float4 pv0, pv1, pv2;
    {
        int gbase = ((bn >> 3) & 31) * 1536 + t;
        const float4* WoR = (const float4*)Wo;
        const float4* W1R = (const float4*)W1;
        const float4* W2R = (const float4*)W2;
        int g0 = gbase, g1 = gbase + 512, g2 = gbase + 1024;
        pv0 = (g0 < 16384) ? WoR[g0] : ((g0 < 32768) ? W1R[g0 - 16384] : W2R[g0 - 32768]);
        pv1 = (g1 < 16384) ? WoR[g1] : ((g1 < 32768) ? W1R[g1 - 16384] : W2R[g1 - 32768]);
        pv2 = (g2 < 16384) ? WoR[g2] : ((g2 < 32768) ? W1R[g2 - 16384] : W2R[g2 - 32768]);
    }

    float nd = 0.0f;
    if (own) {
        int idx = indices[bn];
        nd = (d < NF) ? atom_emb[idx * NF + d] : noise[0];
        nodes[bn * DIMM + d] = nd;
    }
    ln_qkv_pf(nd, own, t, bn, 0, ln1_g, ln1_b, Wq, bq, Wkv, bkv, qb, kb, vb,
              s_xn, s_red, s_part);

    float pf = pv0.x + pv0.y + pv0.z + pv0.w
             + pv1.x + pv1.y + pv1.z + pv1.w
             + pv2.x + pv2.y + pv2.z + pv2.w;
    if (pf == 1.602176634e+30f) nodes[0] = pf;   // never true
}

// Fused per-layer kernel: attention + post pipeline + next-layer QKV.
// Prefetches next layer's weights into L2 at kernel start.
__global__ __launch_bounds__(512, 2) void k_layer(int layer,
        const float* coords, const int* bonds,
        const float* We, const float* be,
        float* qb, const float* kin, const float* vin,
        float* kout, float* vout,
        const float* Wo, const float* bo, const float* Wg1,
        const float* ln2_g, const float* ln2_b,
        const float* W1, const float* b1,
        const float* W2, const float* b2,
        const float* Wg2,
        const float* ln1_g, const float* ln1_b,
        const float* Wq, const float* bq,
        const float* Wkv, const float* bkv,
        float* nodes) {
    int bn = blockIdx.x;
    int b = bn >> 7, i = bn & 127;
    int t = threadIdx.x;
    int d = t & 127;
    bool own = (t < 128);

    __shared__ float scoord[3 * NN];
    __shared__ float sedge[3 * NN];
    __shared__ int   sadj[NN];
    __shared__ float s_o[4 * INNER];
    __shared__ float s_l[4 * HEADS];
    __shared__ float s_ao[INNER];
    __shared__ float s_h[INNER];
    __shared__ float s_xn[128];
    __shared__ float s_red[8];
    __shared__ float s_part[6144];

    // ---- L2 prefetch of NEXT layer's weights (6 float4/thread, stripe by block group)
    int nl = (layer + 1) % DEPTH;
    float4 pv[6];
    {
        int gbase = ((bn >> 3) & 31) * 3072 + t;
        const float4* WqN  = (const float4*)(Wq  + (size_t)nl * DIMM * INNER);
        const float4* WkvN = (const float4*)(Wkv + (size_t)nl * DIMM * 2 * INNER);
        const float4* WoN  = (const float4*)(Wo  + (size_t)nl * INNER * DIMM);
        const float4* W1N  = (const float4*)(W1  + (size_t)nl * DIMM * 4 * DIMM);
        const float4* W2N  = (const float4*)(W2  + (size_t)nl * 4 * DIMM * DIMM);
#pragma unroll
        for (int p = 0; p < 6; p++) {
            int g = gbase + p * 512;   // 0..98303
            const float4* src;
            int off;
            if (g < 16384)      { src = WqN;  off = g; }
            else if (g < 49152) { src = WkvN; off = g - 16384; }
            else if (g < 65536) { src = WoN;  off = g - 49152; }
            else if (g < 81920) { src = W1N;  off = g - 65536; }
            else                { src = W2N;  off = g - 81920; }
            pv[p] = src[off];
        }
    }

    // ---------- Phase A: attention ----------
    int jg = t >> 7;     // 0..3, each handles 32 j's
    int c  = t & 127;    // head-dim quad; head h = c>>4
    int h  = c >> 4;

    const float4* qR  = (const float4*)(qb + (size_t)bn * INNER);
    const float4* WeR = (const float4*)(We + (size_t)layer * 3 * INNER);
    float4 qv  = qR[c];
    float4 we0 = WeR[c], we1 = WeR[128 + c], we2 = WeR[256 + c];
    float4 bev = ((const float4*)(be + (size_t)layer * INNER))[c];
    float res = own ? nodes[bn * DIMM + d] : 0.0f;

    if (t < 3 * NN) scoord[t] = coords[b * 3 * NN + t];
    if (t < NN) sadj[t] = 0;
    __syncthreads();
    if (t < EE) {
        int e0 = bonds[2 * t], e1 = bonds[2 * t + 1];
        if (e0 == i) sadj[e1] = 1;
        if (e1 == i) sadj[e0] = 1;
    }
    __syncthreads();
    if (t < NN) {
        int j = t;
        float msk = sadj[j] ? 1.0f : 0.0f;
        sedge[3 * j + 0] = msk * (scoord[3 * i + 0] - scoord[3 * j + 0]);
        sedge[3 * j + 1] = msk * (scoord[3 * i + 1] - scoord[3 * j + 1]);
        sedge[3 * j + 2] = msk * (scoord[3 * i + 2] - scoord[3 * j + 2]);
    }
    __syncthreads();

    const float4* kR = (const float4*)(kin + (size_t)b * NN * INNER);
    const float4* vR = (const float4*)(vin + (size_t)b * NN * INNER);

    float l_run = 0.0f;
    float4 o_run = {0, 0, 0, 0};
    int j0 = jg * 32;
#pragma unroll
    for (int base = 0; base < 32; base += 8) {
        float4 kvv[8], vvv[8];
#pragma unroll
        for (int p = 0; p < 8; p++) {
            int j = j0 + base + p;
            kvv[p] = kR[j * 128 + c];
            vvv[p] = vR[j * 128 + c];
        }
#pragma unroll
        for (int p = 0; p < 8; p++) {
            int j = j0 + base + p;
            float ex = sedge[3 * j], ey = sedge[3 * j + 1], ez = sedge[3 * j + 2];
            float4 e;
            e.x = bev.x + ex * we0.x + ey * we1.x + ez * we2.x;
            e.y = bev.y + ex * we0.y + ey * we1.y + ez * we2.y;
            e.z = bev.z + ex * we0.z + ey * we1.z + ez * we2.z;
            e.w = bev.w + ex * we0.w + ey * we1.w + ez * we2.w;
            float4 kv = kvv[p];
            float s = (qv.x * (kv.x + e.x) + qv.y * (kv.y + e.y))
                    + (qv.z * (kv.z + e.z) + qv.w * (kv.w + e.w));
            s += __shfl_xor(s, 1, 64);
            s += __shfl_xor(s, 2, 64);
            s += __shfl_xor(s, 4, 64);
            s += __shfl_xor(s, 8, 64);
            float pp = __expf(s * 0.125f);
            float4 vv = vvv[p];
            l_run += pp;
            o_run.x += pp * (vv.x + e.x);
            o_run.y += pp * (vv.y + e.y);
            o_run.z += pp * (vv.z + e.z);
            o_run.w += pp * (vv.w + e.w);
        }
    }
    ((float4*)(s_o + jg * INNER))[c] = o_run;
    if ((c & 15) == 0) s_l[jg * HEADS + h] = l_run;
    __syncthreads();
    if (jg == 0) {
        float4 o = o_run;
        float l = l_run;
#pragma unroll
        for (int g = 1; g < 4; g++) {
            float4 og = ((float4*)(s_o + g * INNER))[c];
            o.x += og.x; o.y += og.y; o.z += og.z; o.w += og.w;
            l += s_l[g * HEADS + h];
        }
        float inv = 1.0f / l;
        float4 rr; rr.x = o.x * inv; rr.y = o.y * inv; rr.z = o.z * inv; rr.w = o.w * inv;
        ((float4*)s_ao)[c] = rr;
    }
    __syncthreads();

    // ---------- Phase B: post pipeline ----------
    int c5   = t & 31;
    int kg16 = t >> 5;
    {
        const float4* WoR = (const float4*)(Wo + (size_t)layer * INNER * DIMM);
        int kkb = kg16 * 32;
        float4 acc = {0, 0, 0, 0};
#pragma unroll
        for (int base = 0; base < 32; base += 8) {
            float4 w[8];
#pragma unroll
            for (int p = 0; p < 8; p++) w[p] = WoR[(kkb + base + p) * 32 + c5];
#pragma unroll
            for (int p = 0; p < 8; p++) fma4(acc, s_ao[kkb + base + p], w[p]);
        }
        ((float4*)(s_part + kg16 * 128))[c5] = acc;
    }
    __syncthreads();
    float x = 0.0f;
    if (own) {
        x = bo[layer * DIMM + d];
#pragma unroll
        for (int g = 0; g < 16; g++) x += s_part[g * 128 + d];
    }

    const float* Wg1_l = Wg1 + layer * 3 * DIMM;
    float texpr = own ? (x * Wg1_l[d] + res * Wg1_l[DIMM + d] + (x - res) * Wg1_l[2 * DIMM + d]) : 0.0f;
    float g1 = block_reduce_sum_8w(texpr, s_red);
    g1 = 1.0f / (1.0f + __expf(-g1));
    float n1 = x * g1 + res * (1.0f - g1);

    float m   = block_reduce_sum_8w(own ? n1 : 0.0f, s_red) * (1.0f / 128.0f);
    float df  = n1 - m;
    float var = block_reduce_sum_8w(own ? df * df : 0.0f, s_red) * (1.0f / 128.0f);
    float xn  = df * rsqrtf(var + 1e-5f) * ln2_g[layer * DIMM + d] + ln2_b[layer * DIMM + d];
    if (own) s_xn[d] = xn;
    __syncthreads();

    int c7  = t & 127;
    int kg4 = t >> 7;
    {
        const float4* W1R = (const float4*)(W1 + (size_t)layer * DIMM * 4 * DIMM);
        int kkb = kg4 * 32;
        float4 acc = {0, 0, 0, 0};
#pragma unroll
        for (int base = 0; base < 32; base += 8) {
            float4 w[8];
#pragma unroll
            for (int p = 0; p < 8; p++) w[p] = W1R[(kkb + base + p) * 128 + c7];
#pragma unroll
            for (int p = 0; p < 8; p++) fma4(acc, s_xn[kkb + base + p], w[p]);
        }
        ((float4*)(s_part + kg4 * 512))[c7] = acc;
    }
    __syncthreads();
    {
        float a = b1[layer * 4 * DIMM + t];
#pragma unroll
        for (int g = 0; g < 4; g++) a += s_part[g * 512 + t];
        a = 0.5f * a * (1.0f + erff(a * 0.70710678f));
        s_h[t] = a;
    }
    __syncthreads();

    {
        const float4* W2R = (const float4*)(W2 + (size_t)layer * 4 * DIMM * DIMM);
        int kkb = kg16 * 32;
        float4 acc = {0, 0, 0, 0};
#pragma unroll
        for (int base = 0; base < 32; base += 8) {
            float4 w[8];
#pragma unroll
            for (int p = 0; p < 8; p++) w[p] = W2R[(kkb + base + p) * 32 + c5];
#pragma unroll
            for (int p = 0; p < 8; p++) fma4(acc, s_h[kkb + base + p], w[p]);
        }
        ((float4*)(s_part + kg16 * 128))[c5] = acc;
    }
    __syncthreads();
    float y = 0.0f;
    if (own) {
        y = b2[layer * DIMM + d];
#pragma unroll
        for (int g = 0; g < 16; g++) y += s_part[g * 128 + d];
    }

    const float* Wg2_l = Wg2 + layer * 3 * DIMM;
    texpr = own ? (y * Wg2_l[d] + n1 * Wg2_l[DIMM + d] + (y - n1) * Wg2_l[2 * DIMM + d]) : 0.0f;
    float g2 = block_reduce_sum_8w(texpr, s_red);
    g2 = 1.0f / (1.0f + __expf(-g2));
    float n2 = y * g2 + n1 * (1.0f - g2);
    if (own) nodes[bn * DIMM + d] = n2;

    if (layer < DEPTH - 1) {
        ln_qkv_pf(own ? n2 : 0.0f, own, t, bn, layer + 1, ln1_g, ln1_b, Wq, bq, Wkv, bkv,
                  qb, kout, vout, s_xn, s_red, s_part);
    }

    // consume prefetch registers (never true -> no write, no DCE)
    float pf = 0.0f;
#pragma unroll
    for (int p = 0; p < 6; p++) pf += pv[p].x + pv[p].y + pv[p].z + pv[p].w;
    if (pf == 1.602176634e+30f) nodes[0] = pf;
}

// Final: sum over nodes of (nodes @ Wlin + blin) -> scalar.
__global__ __launch_bounds__(256) void k_final(const float* nodes, const float* Wlin,
                                               const float* blin, float* out) {
    int t = threadIdx.x; // node index
    __shared__ float s_w[DIMM];
    if (t < DIMM) s_w[t] = Wlin[t];
    __syncthreads();
    float s = blin[0];
    const float4* nr = (const float4*)(nodes + t * DIMM);
#pragma unroll 8
    for (int q = 0; q < 32; q++) {
        float4 n = nr[q];
        s += n.x * s_w[4 * q] + n.y * s_w[4 * q + 1] + n.z * s_w[4 * q + 2] + n.w * s_w[4 * q + 3];
    }
#pragma unroll
    for (int off = 32; off > 0; off >>= 1) s += __shfl_xor(s, off, 64);
    __shared__ float sb[4];
    int wave = t >> 6, lane = t & 63;
    if (lane == 0) sb[wave] = s;
    __syncthreads();
    if (t == 0) out[0] = sb[0] + sb[1] + sb[2] + sb[3];
}

extern "C" void kernel_launch(void* const* d_in, const int* in_sizes, int n_in,
                              void* d_out, int out_size, void* d_ws, size_t ws_size,
                              hipStream_t stream) {
    const int*   indices = (const int*)d_in[0];
    const float* coords  = (const float*)d_in[1];
    const int*   bonds   = (const int*)d_in[2];
    const float* noise   = (const float*)d_in[3];
    const float* atom_emb= (const float*)d_in[4];
    const float* ln1_g   = (const float*)d_in[5];
    const float* ln1_b   = (const float*)d_in[6];
    const float* Wq      = (const float*)d_in[7];
    const float* bq      = (const float*)d_in[8];
    const float* Wkv     = (const float*)d_in[9];
    const float* bkv     = (const float*)d_in[10];
    const float* We      = (const float*)d_in[11];
    const float* be      = (const float*)d_in[12];
    const float* Wo      = (const float*)d_in[13];
    const float* bo      = (const float*)d_in[14];
    const float* Wg1     = (const float*)d_in[15];
    const float* ln2_g   = (const float*)d_in[16];
    const float* ln2_b   = (const float*)d_in[17];
    const float* W1      = (const float*)d_in[18];
    const float* b1      = (const float*)d_in[19];
    const float* W2      = (const float*)d_in[20];
    const float* b2      = (const float*)d_in[21];
    const float* Wg2     = (const float*)d_in[22];
    const float* Wlin    = (const float*)d_in[23];
    const float* blin    = (const float*)d_in[24];

    float* ws    = (float*)d_ws;
    float* nodes = ws;                       // 32768 floats
    float* qb    = nodes + BB * NN * DIMM;   // 131072 floats
    float* kb    = qb + KV_SLAB;             // 2 slabs
    float* vb    = kb + 2 * KV_SLAB;         // 2 slabs

    k_warm<<<256, 512, 0, stream>>>(Wq, Wkv, Wo, W1, W2, We, atom_emb, ws);
    k_pre<<<BB * NN, 512, 0, stream>>>(indices, noise, atom_emb, ln1_g, ln1_b,
                                       Wq, bq, Wkv, bkv, Wo, W1, W2,
                                       nodes, qb, kb, vb);
    for (int l = 0; l < DEPTH; l++) {
        const float* kin = kb + (size_t)(l & 1) * KV_SLAB;
        const float* vin = vb + (size_t)(l & 1) * KV_SLAB;
        float* kout = kb + (size_t)((l + 1) & 1) * KV_SLAB;
        float* vout = vb + (size_t)((l + 1) & 1) * KV_SLAB;
        k_layer<<<BB * NN, 512, 0, stream>>>(l, coords, bonds, We, be,
                                             qb, kin, vin, kout, vout,
                                             Wo, bo, Wg1, ln2_g, ln2_b, W1, b1, W2, b2,
                                             Wg2, ln1_g, ln1_b, Wq, bq, Wkv, bkv, nodes);
    }
    k_final<<<1, 256, 0, stream>>>(nodes, Wlin, blin, (float*)d_out);
}